// Round 1
// baseline (648.617 us; speedup 1.0000x reference)
//
#include <hip/hip_runtime.h>

// Space-to-depth k=2 on (32,224,224,64) fp32 NHWC -> (32,112,112,256),
// output channel order (kh, kw, C).
//
// out[b][ho][wo][(kh*2+kw)*64 + c] = in[b][2*ho+kh][2*wo+kw][c]
//
// v2: 8x batch-strided unroll. Each thread moves 8 float4 (128 B each way)
// instead of 1, giving 8 independent loads in flight (MLP=8) and cutting
// workgroup count 100,352 -> 12,544. The unroll stride S = total4/8 =
// 3,211,264 float4 is a multiple of 64 (channel vec), 112 (wo), and 4*112
// (ho), so c4/wo/ho are invariant across the unroll: only b advances by 4
// per step, and BOTH src and dst advance by the same constant S. One
// div/mod chain per thread total.
//
// Coalescing (unchanged from v1, per unroll step): lanes 0..31 read 512 B
// contiguous from input row 2ho, lanes 32..63 read 512 B contiguous from
// row 2ho+1; the wave writes 1 KB contiguous.

constexpr int U = 8;
constexpr int STRIDE4 = 32 * 224 * 224 * 64 / 4 / U;  // 3,211,264

__global__ __launch_bounds__(256) void s2d_kernel(
    const float4* __restrict__ in, float4* __restrict__ out) {
    int base = blockIdx.x * 256 + threadIdx.x;  // float4 index in out, u=0

    int c4  = base & 63;   // which float4 within the 256-float output vector
    int pos = base >> 6;   // linear (b0, ho, wo), b0 in [0,4)
    int wo  = pos % 112;
    int t   = pos / 112;
    int ho  = t % 112;
    int b0  = t / 112;

    int kh = c4 >> 5;         // c4 in [0,32) -> kh=0, [32,64) -> kh=1
    int kw = (c4 >> 4) & 1;   // within kh: first 16 float4s kw=0, next 16 kw=1
    int cc = c4 & 15;         // float4 index within the 64-channel segment

    int h = 2 * ho + kh;
    int w = 2 * wo + kw;
    // input flat float4 index for b0: ((b*224 + h)*224 + w)*16 + cc
    int src = (((b0 * 224) + h) * 224 + w) * 16 + cc;

    // 8 independent loads first (fill the memory pipe), then 8 stores.
    float4 v[U];
#pragma unroll
    for (int u = 0; u < U; ++u) v[u] = in[src + u * STRIDE4];
#pragma unroll
    for (int u = 0; u < U; ++u) out[base + u * STRIDE4] = v[u];
}

extern "C" void kernel_launch(void* const* d_in, const int* in_sizes, int n_in,
                              void* d_out, int out_size, void* d_ws, size_t ws_size,
                              hipStream_t stream) {
    const float4* in  = (const float4*)d_in[0];
    float4*       out = (float4*)d_out;

    // total float4 = 25,690,112 ; per thread = 8 ; threads = 3,211,264
    const int threads = 256;
    const int blocks  = STRIDE4 / threads;  // 12,544 exactly

    s2d_kernel<<<blocks, threads, 0, stream>>>(in, out);
}